// Round 22
// baseline (465.525 us; speedup 1.0000x reference)
//
#include <hip/hip_runtime.h>
#include <hip/hip_bf16.h>
#include <math.h>

#define N_DOC 4
#define C_    1024
#define D_    768
#define H_    12
#define E_    40
#define M_    3
#define P_    800
#define NP_   3200
#define EMB_  768
#define NREL_ 97
#define IN2_  1536   // 2*D

#define GLOAD_LDS16(g, l) \
  __builtin_amdgcn_global_load_lds( \
      (const __attribute__((address_space(1))) void*)(g), \
      (__attribute__((address_space(3))) void*)(l), 16, 0, 0)

typedef __attribute__((ext_vector_type(8))) short bf16x8;
typedef __attribute__((ext_vector_type(4))) float f32x4;
typedef __attribute__((ext_vector_type(4))) unsigned u32x4;

static __device__ __forceinline__ unsigned short f2bf(float x) {
  unsigned u = __builtin_bit_cast(unsigned, x);
  u = (u + 0x7FFFu + ((u >> 16) & 1u)) >> 16;
  return (unsigned short)u;
}
static __device__ __forceinline__ float bf2f(unsigned short b) {
  unsigned u = ((unsigned)b) << 16;
  return __builtin_bit_cast(float, u);
}

// Fast 8-element hi/lo bf16 split via v_cvt_pk_bf16_f32 (1 instr per 2 elems).
static __device__ __forceinline__ void split8(const float* x, bf16x8* hi, bf16x8* lo) {
  unsigned h[4], l[4];
#pragma unroll
  for (int i = 0; i < 4; ++i) {
    float a = x[2 * i], b = x[2 * i + 1];
    unsigned hp;
    asm("v_cvt_pk_bf16_f32 %0, %1, %2" : "=v"(hp) : "v"(a), "v"(b));
    float af = __builtin_bit_cast(float, hp << 16);
    float bf_ = __builtin_bit_cast(float, hp & 0xffff0000u);
    float ar = a - af, br = b - bf_;
    unsigned lp;
    asm("v_cvt_pk_bf16_f32 %0, %1, %2" : "=v"(lp) : "v"(ar), "v"(br));
    h[i] = hp; l[i] = lp;
  }
  u32x4 hv = {h[0], h[1], h[2], h[3]};
  u32x4 lv = {l[0], l[1], l[2], l[3]};
  *hi = __builtin_bit_cast(bf16x8, hv);
  *lo = __builtin_bit_cast(bf16x8, lv);
}

// ---------------------------------------------------------------- A: ent_emb
__global__ void k_ent_emb(const float* __restrict__ seq, const int* __restrict__ mpos,
                          float* __restrict__ ent_emb) {
  int ne = blockIdx.x;                 // 0..159
  int n = ne / E_, e = ne % E_;
  int base = (n * E_ + e) * M_;
  int p0 = mpos[base + 0] + 1, p1 = mpos[base + 1] + 1, p2 = mpos[base + 2] + 1;
  const float* s0 = seq + ((size_t)n * C_ + p0) * D_;
  const float* s1 = seq + ((size_t)n * C_ + p1) * D_;
  const float* s2 = seq + ((size_t)n * C_ + p2) * D_;
  float* out = ent_emb + (size_t)ne * D_;
  for (int d = threadIdx.x; d < D_; d += blockDim.x) {
    double a = s0[d], b = s1[d], c = s2[d];
    double mx = fmax(a, fmax(b, c));
    double s = exp(a - mx) + exp(b - mx) + exp(c - mx);
    out[d] = (float)(mx + log(s));
  }
}

// ---------------------------------------------------------------- B: ent_att
__global__ void k_ent_att(const float* __restrict__ att, const int* __restrict__ mpos,
                          float* __restrict__ ent_att) {
  int idx = blockIdx.x * 256 + threadIdx.x;        // exactly N*E*H*C = 1966080
  int c = idx & (C_ - 1);
  int h = (idx >> 10) % H_;
  int rem = idx / (C_ * H_);
  int e = rem % E_;
  int n = rem / E_;
  int base = (n * E_ + e) * M_;
  float acc = 0.f;
#pragma unroll
  for (int m = 0; m < M_; ++m) {
    int p = mpos[base + m] + 1;
    acc += att[(((size_t)n * H_ + h) * C_ + p) * C_ + c];
  }
  ent_att[idx] = acc / 3.0f;
}

// ---------------------------------------------------------------- C: ht_att
__global__ void k_ht_att(const float* __restrict__ ent_att, const int* __restrict__ hts,
                         float* __restrict__ ht) {
  int np = blockIdx.x;                 // 0..3199
  int n = np / P_;
  int hi = hts[np * 2 + 0], ti = hts[np * 2 + 1];
  const float* ea_h = ent_att + (size_t)(n * E_ + hi) * H_ * C_;
  const float* ea_t = ent_att + (size_t)(n * E_ + ti) * H_ * C_;
  const int t = threadIdx.x;           // 0..63
  float4 v[4];
  float local = 0.f;
#pragma unroll
  for (int q = 0; q < 4; ++q) {
    int c = t * 4 + 256 * q;
    float4 a = {0.f, 0.f, 0.f, 0.f};
#pragma unroll
    for (int h = 0; h < H_; ++h) {
      float4 x = *(const float4*)(ea_h + (size_t)h * C_ + c);
      float4 y = *(const float4*)(ea_t + (size_t)h * C_ + c);
      a.x += x.x * y.x; a.y += x.y * y.y; a.z += x.z * y.z; a.w += x.w * y.w;
    }
    a.x /= 12.f; a.y /= 12.f; a.z /= 12.f; a.w /= 12.f;
    v[q] = a;
    local += a.x + a.y + a.z + a.w;
  }
  float s = local;
#pragma unroll
  for (int m = 32; m > 0; m >>= 1) s += __shfl_xor(s, m);
  float S = s + 1e-5f;
#pragma unroll
  for (int q = 0; q < 4; ++q) {
    int c = t * 4 + 256 * q;
    float4 o;
    o.x = v[q].x / S; o.y = v[q].y / S; o.z = v[q].z / S; o.w = v[q].w / S;
    *(float4*)&ht[(size_t)np * C_ + c] = o;
  }
}

// ---------------------------------------------------------------- D (fallback): rs GEMM
__global__ void k_rs(const float* __restrict__ ht, const float* __restrict__ seq,
                     float* __restrict__ rs) {
  const int pt0 = blockIdx.x * 16;     // 200 tiles
  const int n = pt0 / P_;
  const int ot = threadIdx.x & 63;
  const int jt = threadIdx.x >> 6;     // 0..3
  const int o4 = blockIdx.y * 256 + ot * 4;
  __shared__ float hlds[16 * 66];
  float4 a32[4];
  double a64[4][4];
#pragma unroll
  for (int q = 0; q < 4; ++q) {
    a32[q] = {0.f, 0.f, 0.f, 0.f};
#pragma unroll
    for (int i = 0; i < 4; ++i) a64[q][i] = 0.0;
  }
  const float* seqn = seq + (size_t)n * C_ * D_;
  for (int c0 = 0; c0 < C_; c0 += 64) {
    for (int l = threadIdx.x; l < 1024; l += 256) {
      int j = l >> 6, cc = l & 63;
      hlds[j * 66 + cc] = ht[(size_t)(pt0 + j) * C_ + c0 + cc];
    }
    __syncthreads();
#pragma unroll 4
    for (int cc = 0; cc < 64; ++cc) {
      float4 sv = *(const float4*)&seqn[(size_t)(c0 + cc) * D_ + o4];
#pragma unroll
      for (int q = 0; q < 4; ++q) {
        float w = hlds[(jt * 4 + q) * 66 + cc];
        a32[q].x += w * sv.x; a32[q].y += w * sv.y;
        a32[q].z += w * sv.z; a32[q].w += w * sv.w;
      }
    }
#pragma unroll
    for (int q = 0; q < 4; ++q) {
      a64[q][0] += (double)a32[q].x; a64[q][1] += (double)a32[q].y;
      a64[q][2] += (double)a32[q].z; a64[q][3] += (double)a32[q].w;
      a32[q] = {0.f, 0.f, 0.f, 0.f};
    }
    __syncthreads();
  }
#pragma unroll
  for (int q = 0; q < 4; ++q) {
    int p = pt0 + jt * 4 + q;
#pragma unroll
    for (int i = 0; i < 4; ++i)
      rs[(size_t)p * D_ + o4 + i] = (float)a64[q][i];
  }
}

// ---------------------------------------------------------------- seq-split prep (rs B operand)
__global__ void k_wsplit_rs(const float* __restrict__ seq,
                            unsigned short* __restrict__ Shi,
                            unsigned short* __restrict__ Slo) {
  int g = blockIdx.x * 256 + threadIdx.x;          // 0..393215
  int l = g & 63;
  int n = (g >> 6) % 48;
  int T = (g >> 6) / 48 % 32;
  int doc = g / 98304;
  int k0 = T * 32 + (l >> 4) * 8;
  int o = n * 16 + (l & 15);
  size_t off = (size_t)g * 8;
#pragma unroll
  for (int e = 0; e < 8; ++e) {
    float v = seq[((size_t)doc * C_ + k0 + e) * D_ + o];
    unsigned short hi = f2bf(v);
    unsigned short lo = f2bf(v - bf2f(hi));
    Shi[off + e] = hi;
    Slo[off + e] = lo;
  }
}

// ---------------------------------------------------------------- D': rs via MFMA
__global__ __launch_bounds__(256) void k_rs_mfma(
    const float* __restrict__ ht,
    const unsigned short* __restrict__ Shi, const unsigned short* __restrict__ Slo,
    float* __restrict__ rs) {
  const int pt  = blockIdx.x;          // 0..99
  const int doc = pt / 25;
  const int n0  = blockIdx.y * 12;
  const int tid = threadIdx.x;
  const int w   = tid >> 6;
  const int l   = tid & 63;
  const int rg  = w & 1, cg = w >> 1;
  const int kg  = l >> 4;
  const int pr  = pt * 32 + rg * 16 + (l & 15);
  const float* htrow = ht + (size_t)pr * C_;

  __shared__ __align__(16) unsigned short ldsW[2][12288];  // 2 x 24576 B

  auto stage = [&](int buf, int T) {
#pragma unroll
    for (int rr = 0; rr < 6; ++rr) {
      int u = rr * 256 + tid;          // 0..1535
      int term = u / 768, rem = u % 768;
      int nn = rem >> 6, lu = rem & 63;
      const unsigned short* src = (term ? Slo : Shi) +
          (((size_t)(doc * 32 + T) * 48 + n0 + nn) * 64 + lu) * 8;
      GLOAD_LDS16(src, &ldsW[buf][u * 8]);
    }
  };

  f32x4 acc[6];
#pragma unroll
  for (int nn = 0; nn < 6; ++nn) acc[nn] = (f32x4){0.f, 0.f, 0.f, 0.f};

  stage(0, 0);
  __syncthreads();

  int cur = 0;
#pragma unroll 1
  for (int T = 0; T < 32; ++T) {
    if (T < 31) stage(cur ^ 1, T + 1);

    int kx = T * 32 + kg * 8;
    float4 z0 = *(const float4*)(htrow + kx);
    float4 z1 = *(const float4*)(htrow + kx + 4);
    float zv[8] = {z0.x, z0.y, z0.z, z0.w, z1.x, z1.y, z1.z, z1.w};
    bf16x8 ahi, alo;
    split8(zv, &ahi, &alo);

    const unsigned short* lp = ldsW[cur];
#pragma unroll
    for (int nn = 0; nn < 6; ++nn) {
      int nt = cg * 6 + nn;
      bf16x8 bh = *(const bf16x8*)(lp + ((size_t)(nt * 64 + l)) * 8);
      bf16x8 bl = *(const bf16x8*)(lp + 6144 + ((size_t)(nt * 64 + l)) * 8);
      acc[nn] = __builtin_amdgcn_mfma_f32_16x16x32_bf16(ahi, bh, acc[nn], 0, 0, 0);
      acc[nn] = __builtin_amdgcn_mfma_f32_16x16x32_bf16(ahi, bl, acc[nn], 0, 0, 0);
      acc[nn] = __builtin_amdgcn_mfma_f32_16x16x32_bf16(alo, bh, acc[nn], 0, 0, 0);
    }
    __syncthreads();
    cur ^= 1;
  }

  const int colr = l & 15, rowg = (l >> 4) * 4;
#pragma unroll
  for (int nn = 0; nn < 6; ++nn)
#pragma unroll
    for (int i = 0; i < 4; ++i) {
      int p = pt * 32 + rg * 16 + rowg + i;
      int o = (n0 + cg * 6 + nn) * 16 + colr;
      rs[(size_t)p * D_ + o] = acc[nn][i];
    }
}

// ---------------------------------------------------------------- E (fallback): zh & zt merged
__global__ void k_zht(const float* __restrict__ ent_emb, const float* __restrict__ rs,
                      const int* __restrict__ hts,
                      const float* __restrict__ Wh_, const float* __restrict__ bh_,
                      const float* __restrict__ Wt_, const float* __restrict__ bt_,
                      float* __restrict__ zh_, float* __restrict__ zt_) {
  const int which = blockIdx.z;        // 0 -> zh, 1 -> zt
  const float* W    = which ? Wt_ : Wh_;
  const float* bias = which ? bt_ : bh_;
  float* out        = which ? zt_ : zh_;
  const int dbl_tanh = which ^ 1;
  const int pt0 = blockIdx.x * 16;
  const int n = pt0 / P_;
  const int ot = threadIdx.x & 63;
  const int jt = threadIdx.x >> 6;
  const int o4 = blockIdx.y * 256 + ot * 4;
  __shared__ float xlds[16 * 66];
  __shared__ int sidx[16];
  if (threadIdx.x < 16) sidx[threadIdx.x] = hts[(pt0 + threadIdx.x) * 2 + which];
  float4 a32[4];
  double a64[4][4];
#pragma unroll
  for (int q = 0; q < 4; ++q) {
    a32[q] = {0.f, 0.f, 0.f, 0.f};
#pragma unroll
    for (int i = 0; i < 4; ++i) a64[q][i] = 0.0;
  }
  __syncthreads();
  for (int k0 = 0; k0 < IN2_; k0 += 64) {
    for (int l = threadIdx.x; l < 1024; l += 256) {
      int j = l >> 6, q = l & 63;
      int kx = k0 + q;
      float val;
      if (kx < D_) val = ent_emb[(size_t)(n * E_ + sidx[j]) * D_ + kx];
      else         val = rs[(size_t)(pt0 + j) * D_ + (kx - D_)];
      xlds[j * 66 + q] = val;
    }
    __syncthreads();
#pragma unroll 4
    for (int q = 0; q < 64; ++q) {
      float4 wv = *(const float4*)&W[(size_t)(k0 + q) * EMB_ + o4];
#pragma unroll
      for (int j = 0; j < 4; ++j) {
        float x = xlds[(jt * 4 + j) * 66 + q];
        a32[j].x += x * wv.x; a32[j].y += x * wv.y;
        a32[j].z += x * wv.z; a32[j].w += x * wv.w;
      }
    }
#pragma unroll
    for (int j = 0; j < 4; ++j) {
      a64[j][0] += (double)a32[j].x; a64[j][1] += (double)a32[j].y;
      a64[j][2] += (double)a32[j].z; a64[j][3] += (double)a32[j].w;
      a32[j] = {0.f, 0.f, 0.f, 0.f};
    }
    __syncthreads();
  }
#pragma unroll
  for (int j = 0; j < 4; ++j) {
    int p = pt0 + jt * 4 + j;
#pragma unroll
    for (int i = 0; i < 4; ++i) {
      int o = o4 + i;
      double z = a64[j][i] + (double)bias[o];
      z = tanh(z);
      if (dbl_tanh) z = tanh(z);
      out[(size_t)p * EMB_ + o] = (float)z;
    }
  }
}

// ---------------------------------------------------------------- W-split prep (logits Wb)
__global__ void k_wsplit(const float* __restrict__ Wb,
                         unsigned short* __restrict__ Whi,
                         unsigned short* __restrict__ Wlo) {
  int g = blockIdx.x * 256 + threadIdx.x;          // 0..589823
  int l = g & 63;
  int n = (g >> 6) % 6;
  int T = (g >> 6) / 6 % 128;
  int k12 = g / 49152;
  int kk = (T >> 1) * 64 + (T & 1) * 32 + (l >> 4) * 8;
  int row0 = k12 * 4096 + kk;
  int r = n * 16 + (l & 15);
  size_t o = (size_t)g * 8;
#pragma unroll
  for (int e = 0; e < 8; ++e) {
    float v = Wb[(size_t)(row0 + e) * NREL_ + r];
    unsigned short hi = f2bf(v);
    unsigned short lo = f2bf(v - bf2f(hi));
    Whi[o + e] = hi;
    Wlo[o + e] = lo;
  }
}

// ---------------------------------------------------------------- pack W col 96
__global__ void k_pack96(const float* __restrict__ Wb, float* __restrict__ W96c) {
  int g = blockIdx.x * 256 + threadIdx.x;          // 0..49151
  W96c[g] = Wb[(size_t)g * NREL_ + 96];
}

// ---------------------------------------------------------------- W-split prep (zht Wh/Wt)
__global__ void k_wsplit_zht(const float* __restrict__ Wh_, const float* __restrict__ Wt_,
                             unsigned short* __restrict__ Zhi,
                             unsigned short* __restrict__ Zlo) {
  int g = blockIdx.x * 256 + threadIdx.x;          // 0..294911
  int which = g / 147456;
  int rem = g % 147456;
  int l = rem & 63;
  int n = (rem >> 6) % 48;
  int T = (rem >> 6) / 48;
  const float* W = which ? Wt_ : Wh_;
  int k0 = T * 32 + (l >> 4) * 8;
  int o = n * 16 + (l & 15);
  size_t off = ((size_t)which * 147456 + (size_t)(T * 48 + n) * 64 + l) * 8;
#pragma unroll
  for (int e = 0; e < 8; ++e) {
    float v = W[(size_t)(k0 + e) * EMB_ + o];
    unsigned short hi = f2bf(v);
    unsigned short lo = f2bf(v - bf2f(hi));
    Zhi[off + e] = hi;
    Zlo[off + e] = lo;
  }
}

// ---------------------------------------------------------------- E': zh & zt via MFMA
__global__ __launch_bounds__(256) void k_zht_mfma(
    const float* __restrict__ ent_emb, const float* __restrict__ rs,
    const int* __restrict__ hts,
    const unsigned short* __restrict__ Zhi, const unsigned short* __restrict__ Zlo,
    const float* __restrict__ bh_, const float* __restrict__ bt_,
    float* __restrict__ zh_, float* __restrict__ zt_) {
  const int which = blockIdx.z;
  const float* bias = which ? bt_ : bh_;
  float* out = which ? zt_ : zh_;
  const int ptb = blockIdx.x * 64;
  const int n0  = blockIdx.y * 6;      // ntile base (o base = n0*16)
  const int tid = threadIdx.x;
  const int w   = tid >> 6;
  const int l   = tid & 63;
  const int kg  = l >> 4;
  const int pr  = ptb + w * 16 + (l & 15);
  const int doc = pr / P_;
  const int idx = hts[pr * 2 + which];
  const float* eb = ent_emb + (size_t)(doc * E_ + idx) * D_;
  const float* rb = rs + (size_t)pr * D_;

  __shared__ __align__(16) unsigned short ldsW[2][6144];  // 2 x 12288 B

  const unsigned short* Zh = Zhi + (size_t)which * 147456 * 8;
  const unsigned short* Zl = Zlo + (size_t)which * 147456 * 8;

  auto stage = [&](int buf, int T) {
#pragma unroll
    for (int rr = 0; rr < 3; ++rr) {
      int u = rr * 256 + tid;
      int term = u / 384, rem = u % 384;
      int nn = rem >> 6, lu = rem & 63;
      const unsigned short* src = (term ? Zl : Zh) +
          ((size_t)(T * 48 + n0 + nn) * 64 + lu) * 8;
      GLOAD_LDS16(src, &ldsW[buf][u * 8]);
    }
  };

  f32x4 acc[6];
#pragma unroll
  for (int nn = 0; nn < 6; ++nn) acc[nn] = (f32x4){0.f, 0.f, 0.f, 0.f};

  stage(0, 0);
  __syncthreads();

  int cur = 0;
#pragma unroll 1
  for (int T = 0; T < 48; ++T) {
    if (T < 47) stage(cur ^ 1, T + 1);

    int kx = T * 32 + kg * 8;
    const float* src = (T < 24) ? (eb + kx) : (rb + kx - D_);
    float4 z0 = *(const float4*)(src);
    float4 z1 = *(const float4*)(src + 4);
    float zv[8] = {z0.x, z0.y, z0.z, z0.w, z1.x, z1.y, z1.z, z1.w};
    bf16x8 ahi, alo;
    split8(zv, &ahi, &alo);

    const unsigned short* lp = ldsW[cur];
#pragma unroll
    for (int nn = 0; nn < 6; ++nn) {
      bf16x8 bh = *(const bf16x8*)(lp + ((size_t)(nn * 64 + l)) * 8);
      bf16x8 bl = *(const bf16x8*)(lp + ((size_t)(384 + nn * 64 + l)) * 8);
      acc[nn] = __builtin_amdgcn_mfma_f32_16x16x32_bf16(ahi, bh, acc[nn], 0, 0, 0);
      acc[nn] = __builtin_amdgcn_mfma_f32_16x16x32_bf16(ahi, bl, acc[nn], 0, 0, 0);
      acc[nn] = __builtin_amdgcn_mfma_f32_16x16x32_bf16(alo, bh, acc[nn], 0, 0, 0);
    }
    __syncthreads();
    cur ^= 1;
  }

  const int colr = l & 15, rowg = (l >> 4) * 4;
#pragma unroll
  for (int nn = 0; nn < 6; ++nn)
#pragma unroll
    for (int i = 0; i < 4; ++i) {
      int p = ptb + w * 16 + rowg + i;
      int o = (n0 + nn) * 16 + colr;
      double z = (double)acc[nn][i] + (double)bias[o];
      z = tanh(z);
      if (which == 0) z = tanh(z);
      out[(size_t)p * EMB_ + o] = (float)z;
    }
}

// ---------------------------------------------------------------- F: logits via MFMA (r 0..95)
// 512-thread blocks (8 waves, 128-pair tiles), grid 600 = 24 slabs x 25 tiles.
// Per chunk the same 12 KB B-stage now feeds 8 waves (2x compute per barrier,
// half the total staging traffic); wave demand 18.75/CU (4.7/SIMD). Sum order
// and slab partials bit-identical to the 256-thread version.
__global__ __launch_bounds__(512) void k_logits_mfma(
    const float* __restrict__ zh, const float* __restrict__ zt,
    const unsigned short* __restrict__ Whi, const unsigned short* __restrict__ Wlo,
    float* __restrict__ pA) {
  const int bid = blockIdx.x;          // 0..599
  const int s   = bid % 24;            // slab (XCD s%8 affinity)
  const int ptb = (bid / 24) * 128;    // pair-tile base (128 pairs)
  const int k12 = s >> 1, q = s & 1;
  const int tid = threadIdx.x;
  const int w   = tid >> 6;            // wave 0..7
  const int l   = tid & 63;
  const int kg  = l >> 4;
  const int pr  = ptb + w * 16 + (l & 15);

  __shared__ __align__(16) unsigned short ldsW[2][6144];

  auto stage = [&](int buf, int tl) {
    int T = q * 64 + tl;
    size_t fb = (size_t)(k12 * 128 + T) * 6;
    {
      int u = tid;                     // 0..511
      int term = u / 384, rem = u % 384;
      int n = rem >> 6, lu = rem & 63;
      const unsigned short* src = (term ? Wlo : Whi) + ((fb + n) * 64 + lu) * 8;
      GLOAD_LDS16(src, &ldsW[buf][u * 8]);
    }
    if (tid < 256) {
      int u = 512 + tid;               // 512..767
      int term = u / 384, rem = u % 384;
      int n = rem >> 6, lu = rem & 63;
      const unsigned short* src = (term ? Wlo : Whi) + ((fb + n) * 64 + lu) * 8;
      GLOAD_LDS16(src, &ldsW[buf][u * 8]);
    }
  };

  f32x4 acc[6];
#pragma unroll
  for (int n = 0; n < 6; ++n) acc[n] = (f32x4){0.f, 0.f, 0.f, 0.f};

  const float* ztrow = zt + (size_t)pr * EMB_ + k12 * 64;
  const float* zhrow = zh + (size_t)pr * EMB_ + k12 * 64;

  stage(0, 0);
  __syncthreads();

  int cur = 0;
#pragma unroll 1
  for (int tl = 0; tl < 64; ++tl) {
    if (tl < 63) stage(cur ^ 1, tl + 1);

    int T = q * 64 + tl;
    float zhv = zhrow[T >> 1];
    int cbase = (T & 1) * 32 + kg * 8;
    float4 z0 = *(const float4*)(ztrow + cbase);
    float4 z1 = *(const float4*)(ztrow + cbase + 4);
    float pz[8] = {zhv * z0.x, zhv * z0.y, zhv * z0.z, zhv * z0.w,
                   zhv * z1.x, zhv * z1.y, zhv * z1.z, zhv * z1.w};
    bf16x8 ahi, alo;
    split8(pz, &ahi, &alo);

    const unsigned short* lp = ldsW[cur];
#pragma unroll
    for (int n = 0; n < 6; ++n) {
      bf16x8 bh = *(const bf16x8*)(lp + ((size_t)(n * 64 + l)) * 8);
      bf16x8 bl = *(const bf16x8*)(lp + ((size_t)(384 + n * 64 + l)) * 8);
      acc[n] = __builtin_amdgcn_mfma_f32_16x16x32_bf16(ahi, bh, acc[n], 0, 0, 0);
      acc[n] = __builtin_amdgcn_mfma_f32_16x16x32_bf16(ahi, bl, acc[n], 0, 0, 0);
      acc[n] = __builtin_amdgcn_mfma_f32_16x16x32_bf16(alo, bh, acc[n], 0, 0, 0);
    }
    __syncthreads();
    cur ^= 1;
  }

  float* po = pA + (size_t)s * NP_ * NREL_;
  const int colr = l & 15, rowg = (l >> 4) * 4;
#pragma unroll
  for (int n = 0; n < 6; ++n)
#pragma unroll
    for (int i = 0; i < 4; ++i) {
      int p = ptb + w * 16 + rowg + i;
      po[(size_t)p * NREL_ + n * 16 + colr] = acc[n][i];
    }
}

// ---------------------------------------------------------------- F2: r=96 (packed W96c, block per pair)
__global__ void k_r96b(const float* __restrict__ zh, const float* __restrict__ zt,
                       const float* __restrict__ W96c, float* __restrict__ r96o) {
  const int p = blockIdx.x;            // 0..3199
  const int t = threadIdx.x;           // 0..255
  const float* zhr = zh + (size_t)p * EMB_;
  const float* ztr = zt + (size_t)p * EMB_;
  float acc = 0.f;
#pragma unroll
  for (int i = 0; i < 3; ++i) {
    int kk = t + 256 * i;
    float zhv = zhr[kk];
    const float* wseg = W96c + kk * 64;
    const float* zseg = ztr + (kk >> 6) * 64;
    float d = 0.f;
#pragma unroll
    for (int c4 = 0; c4 < 16; ++c4) {
      float4 wv = *(const float4*)(wseg + c4 * 4);
      float4 zv = *(const float4*)(zseg + c4 * 4);
      d += wv.x * zv.x + wv.y * zv.y + wv.z * zv.z + wv.w * zv.w;
    }
    acc += zhv * d;
  }
  __shared__ double red[256];
  red[t] = (double)acc;
  __syncthreads();
  for (int s = 128; s > 0; s >>= 1) {
    if (t < s) red[t] += red[t + s];
    __syncthreads();
  }
  if (t == 0) r96o[p] = (float)red[0];
}

// ---------------------------------------------------------------- G: finalize (MFMA path)
__global__ void k_final_mfma(const float* __restrict__ pA, const float* __restrict__ r96o,
                             const float* __restrict__ bb, float* __restrict__ out) {
  const int p = blockIdx.x;
  const int r = threadIdx.x;           // 128 threads
  __shared__ double th_s;
  __shared__ int cnt[128];
  double v = 0.0;
  if (r < 96) {
    for (int g = 0; g < 24; ++g)
      v += (double)pA[(size_t)g * NP_ * NREL_ + (size_t)p * NREL_ + r];
    v += (double)bb[r];
    out[(size_t)p * NREL_ + r] = (float)v;
  } else if (r == 96) {
    v = (double)r96o[p] + (double)bb[96];
    out[(size_t)p * NREL_ + 96] = (float)v;
  }
  if (r == 0) th_s = v;
  __syncthreads();
  int pred = (r >= 1 && r < NREL_ && v > th_s) ? 1 : 0;
  cnt[r] = pred;
  __syncthreads();
  for (int s = 64; s > 0; s >>= 1) {
    if (r < s) cnt[r] += cnt[r + s];
    __syncthreads();
  }
  if (r < NREL_) {
    float pv = (r == 0) ? ((cnt[0] == 0) ? 1.f : 0.f) : (float)pred;
    out[(size_t)NP_ * NREL_ + (size_t)p * NREL_ + r] = pv;
  }
}

// ---------------------------------------------------------------- Fallback flat logits + final
__global__ __launch_bounds__(256) void k_logits_flat(
    const float* __restrict__ zh, const float* __restrict__ zt,
    const float* __restrict__ Wb, float* __restrict__ part) {
  const int bid = blockIdx.x;
  const int s   = bid % 24;
  const int t   = bid / 24;
  const int k   = s >> 1, bh = s & 1;
  const int pt0 = t * 64;
  const int rt = threadIdx.x & 15;
  const int pg = threadIdx.x >> 4;
  const int kb0 = k * 64 + bh * 32;
  __shared__ float Wlin[64 * 97];
  auto stage_w = [&](int b) {
    const float* src = Wb + (size_t)(kb0 + b) * 6208;
#pragma unroll
    for (int u = 0; u < 6; ++u)
      GLOAD_LDS16(src + (u * 256 + threadIdx.x) * 4,
                  Wlin + (u * 256 + threadIdx.x) * 4);
    if (threadIdx.x < 16)
      GLOAD_LDS16(src + (1536 + threadIdx.x) * 4,
                  Wlin + (1536 + threadIdx.x) * 4);
  };
  stage_w(0);
  float acc[4][6];
  float acc6[4];
#pragma unroll
  for (int j = 0; j < 4; ++j) {
    acc6[j] = 0.f;
#pragma unroll
    for (int i = 0; i < 6; ++i) acc[j][i] = 0.f;
  }
  const float* ztb  = zt + (size_t)(pt0 + pg * 4) * EMB_ + k * 64;
  const float* zh_g = zh + (size_t)(pt0 + pg * 4) * EMB_ + kb0;
  __syncthreads();
#pragma unroll 1
  for (int b = 0; b < 32; ++b) {
    float zhv[4];
#pragma unroll
    for (int j = 0; j < 4; ++j) zhv[j] = zh_g[(size_t)j * EMB_ + b];
#pragma unroll 1
    for (int c0 = 0; c0 < 64; c0 += 4) {
      float4 ztv[4];
#pragma unroll
      for (int j = 0; j < 4; ++j)
        ztv[j] = *(const float4*)(ztb + (size_t)j * EMB_ + c0);
      float4 pz[4];
#pragma unroll
      for (int j = 0; j < 4; ++j) {
        pz[j].x = zhv[j] * ztv[j].x; pz[j].y = zhv[j] * ztv[j].y;
        pz[j].z = zhv[j] * ztv[j].z; pz[j].w = zhv[j] * ztv[j].w;
      }
#pragma unroll
      for (int cc = 0; cc < 4; ++cc) {
        const float* wr = &Wlin[(c0 + cc) * 97];
        float w6 = wr[96];
#pragma unroll
        for (int i = 0; i < 6; ++i) {
          float w = wr[rt + 16 * i];
#pragma unroll
          for (int j = 0; j < 4; ++j) {
            float pzc = (cc == 0) ? pz[j].x : (cc == 1) ? pz[j].y
                      : (cc == 2) ? pz[j].z : pz[j].w;
            acc[j][i] += pzc * w;
          }
        }
#pragma unroll
        for (int j = 0; j < 4; ++j) {
          float pzc = (cc == 0) ? pz[j].x : (cc == 1) ? pz[j].y
                    : (cc == 2) ? pz[j].z : pz[j].w;
          acc6[j] += pzc * w6;
        }
      }
    }
    if (b < 31) {
      __syncthreads();
      stage_w(b + 1);
      __syncthreads();
    }
  }
  float* po = part + (size_t)s * NP_ * NREL_;
#pragma unroll
  for (int j = 0; j < 4; ++j) {
    int p = pt0 + pg * 4 + j;
#pragma unroll
    for (int i = 0; i < 6; ++i)
      po[(size_t)p * NREL_ + rt + 16 * i] = acc[j][i];
    if (rt == 0) po[(size_t)p * NREL_ + 96] = acc6[j];
  }
}

__global__ void k_final_flat(const float* __restrict__ part, const float* __restrict__ bb,
                             float* __restrict__ out) {
  const int p = blockIdx.x;
  const int r = threadIdx.x;
  __shared__ double th_s;
  __shared__ int cnt[128];
  double v = 0.0;
  if (r < NREL_) {
    for (int g = 0; g < 24; ++g)
      v += (double)part[(size_t)g * NP_ * NREL_ + (size_t)p * NREL_ + r];
    v += (double)bb[r];
    out[(size_t)p * NREL_ + r] = (float)v;
  }
  if (r == 0) th_s = v;
  __syncthreads();
  int pred = (r >= 1 && r < NREL_ && v > th_s) ? 1 : 0;
  cnt[r] = pred;
  __syncthreads();
  for (int s = 64; s > 0; s >>= 1) {
    if (r < s) cnt[r] += cnt[r + s];
    __syncthreads();
  }
  if (r < NREL_) {
    float pv = (r == 0) ? ((cnt[0] == 0) ? 1.f : 0.f) : (float)pred;
    out[(size_t)NP_ * NREL_ + (size_t)p * NREL_ + r] = pv;
  }
}

extern "C" void kernel_launch(void* const* d_in, const int* in_sizes, int n_in,
                              void* d_out, int out_size, void* d_ws, size_t ws_size,
                              hipStream_t stream) {
  const float* seq  = (const float*)d_in[0];
  const float* att  = (const float*)d_in[1];
  const int*   mpos = (const int*)d_in[2];
  const int*   hts  = (const int*)d_in[3];
  const float* Wh   = (const float*)d_in[4];
  const float* bh   = (const float*)d_in[5];
  const float* Wt   = (const float*)d_in[6];
  const float* bt   = (const float*)d_in[7];
  const float* Wb   = (const float*)d_in[8];
  const float* bb   = (const float*)d_in[9];
  float* out = (float*)d_out;
  float* ws = (float*)d_ws;

  float* ent_emb = ws;                   // [0, 122880)
  float* ent_att = ws + 122880;          // dead after k_ht_att
  float* ht      = ws + 2088960;         // dead after rs
  float* rs      = ws + 5365760;         // dead after zht
  float* zh      = ws + 7823360;
  float* zt      = ws + 10280960;        // ends 12738560
  // MFMA path layout (float-offsets):
  //   pA    [122880, 7572480)      24 slabs (aliases dead ent_att+ht+rs at logits time)
  //   Shi   [7823360, 9396224)     3,145,728 bf16  } alias zh/zt region: dead
  //   Slo   [9396224, 10969088)    3,145,728 bf16  } before k_zht_mfma writes
  //   r96o  [12738560, 12741760)   3200
  //   Whi   [12815360, 15174656)   4,718,592 bf16
  //   Wlo   [15174656, 17533952)   4,718,592 bf16
  //   Zhi   [17533952, 18713600)   2 x 1,179,648 bf16
  //   Zlo   [18713600, 19893248)   2 x 1,179,648 bf16
  //   W96c  [19893248, 19942400)   49152 fp32
  float* pA   = ws + 122880;
  unsigned short* Shi = (unsigned short*)(ws + 7823360);
  unsigned short* Slo = (unsigned short*)(ws + 9396224);
  float* r96o = ws + 12738560;
  unsigned short* Whi = (unsigned short*)(ws + 12815360);
  unsigned short* Wlo = (unsigned short*)(ws + 15174656);
  unsigned short* Zhi = (unsigned short*)(ws + 17533952);
  unsigned short* Zlo = (unsigned short*)(ws + 18713600);
  float* W96c = ws + 19893248;
  const bool big = ws_size >= (size_t)19942400 * sizeof(float);  // 79.8 MB

  if (big) {
    k_wsplit<<<2304, 256, 0, stream>>>(Wb, Whi, Wlo);
    k_wsplit_zht<<<1152, 256, 0, stream>>>(Wh, Wt, Zhi, Zlo);
    k_wsplit_rs<<<1536, 256, 0, stream>>>(seq, Shi, Slo);
    k_pack96<<<192, 256, 0, stream>>>(Wb, W96c);
  }
  k_ent_emb<<<160, 256, 0, stream>>>(seq, mpos, ent_emb);
  k_ent_att<<<7680, 256, 0, stream>>>(att, mpos, ent_att);
  k_ht_att<<<3200, 64, 0, stream>>>(ent_att, hts, ht);
  if (big) {
    k_rs_mfma<<<dim3(100, 4), 256, 0, stream>>>(ht, Shi, Slo, rs);
    k_zht_mfma<<<dim3(50, 8, 2), 256, 0, stream>>>(ent_emb, rs, hts, Zhi, Zlo,
                                                   bh, bt, zh, zt);
    k_r96b<<<3200, 256, 0, stream>>>(zh, zt, W96c, r96o);
    k_logits_mfma<<<600, 512, 0, stream>>>(zh, zt, Whi, Wlo, pA);
    k_final_mfma<<<3200, 128, 0, stream>>>(pA, r96o, bb, out);
  } else {
    k_rs<<<dim3(200, 3), 256, 0, stream>>>(ht, seq, rs);
    k_zht<<<dim3(200, 3, 2), 256, 0, stream>>>(ent_emb, rs, hts, Wh, bh, Wt, bt, zh, zt);
    k_logits_flat<<<1200, 256, 0, stream>>>(zh, zt, Wb, pA);
    k_final_flat<<<3200, 128, 0, stream>>>(pA, bb, out);
  }
}

// Round 23
// 433.962 us; speedup vs baseline: 1.0727x; 1.0727x over previous
//
#include <hip/hip_runtime.h>
#include <hip/hip_bf16.h>
#include <math.h>

#define N_DOC 4
#define C_    1024
#define D_    768
#define H_    12
#define E_    40
#define M_    3
#define P_    800
#define NP_   3200
#define EMB_  768
#define NREL_ 97
#define IN2_  1536   // 2*D

#define GLOAD_LDS16(g, l) \
  __builtin_amdgcn_global_load_lds( \
      (const __attribute__((address_space(1))) void*)(g), \
      (__attribute__((address_space(3))) void*)(l), 16, 0, 0)

typedef __attribute__((ext_vector_type(8))) short bf16x8;
typedef __attribute__((ext_vector_type(4))) float f32x4;
typedef __attribute__((ext_vector_type(4))) unsigned u32x4;

static __device__ __forceinline__ unsigned short f2bf(float x) {
  unsigned u = __builtin_bit_cast(unsigned, x);
  u = (u + 0x7FFFu + ((u >> 16) & 1u)) >> 16;
  return (unsigned short)u;
}
static __device__ __forceinline__ float bf2f(unsigned short b) {
  unsigned u = ((unsigned)b) << 16;
  return __builtin_bit_cast(float, u);
}

// Fast 8-element hi/lo bf16 split via v_cvt_pk_bf16_f32 (1 instr per 2 elems).
static __device__ __forceinline__ void split8(const float* x, bf16x8* hi, bf16x8* lo) {
  unsigned h[4], l[4];
#pragma unroll
  for (int i = 0; i < 4; ++i) {
    float a = x[2 * i], b = x[2 * i + 1];
    unsigned hp;
    asm("v_cvt_pk_bf16_f32 %0, %1, %2" : "=v"(hp) : "v"(a), "v"(b));
    float af = __builtin_bit_cast(float, hp << 16);
    float bf_ = __builtin_bit_cast(float, hp & 0xffff0000u);
    float ar = a - af, br = b - bf_;
    unsigned lp;
    asm("v_cvt_pk_bf16_f32 %0, %1, %2" : "=v"(lp) : "v"(ar), "v"(br));
    h[i] = hp; l[i] = lp;
  }
  u32x4 hv = {h[0], h[1], h[2], h[3]};
  u32x4 lv = {l[0], l[1], l[2], l[3]};
  *hi = __builtin_bit_cast(bf16x8, hv);
  *lo = __builtin_bit_cast(bf16x8, lv);
}

// ---------------------------------------------------------------- A: ent_emb
__global__ void k_ent_emb(const float* __restrict__ seq, const int* __restrict__ mpos,
                          float* __restrict__ ent_emb) {
  int ne = blockIdx.x;                 // 0..159
  int n = ne / E_, e = ne % E_;
  int base = (n * E_ + e) * M_;
  int p0 = mpos[base + 0] + 1, p1 = mpos[base + 1] + 1, p2 = mpos[base + 2] + 1;
  const float* s0 = seq + ((size_t)n * C_ + p0) * D_;
  const float* s1 = seq + ((size_t)n * C_ + p1) * D_;
  const float* s2 = seq + ((size_t)n * C_ + p2) * D_;
  float* out = ent_emb + (size_t)ne * D_;
  for (int d = threadIdx.x; d < D_; d += blockDim.x) {
    double a = s0[d], b = s1[d], c = s2[d];
    double mx = fmax(a, fmax(b, c));
    double s = exp(a - mx) + exp(b - mx) + exp(c - mx);
    out[d] = (float)(mx + log(s));
  }
}

// ---------------------------------------------------------------- B: ent_att
__global__ void k_ent_att(const float* __restrict__ att, const int* __restrict__ mpos,
                          float* __restrict__ ent_att) {
  int idx = blockIdx.x * 256 + threadIdx.x;        // exactly N*E*H*C = 1966080
  int c = idx & (C_ - 1);
  int h = (idx >> 10) % H_;
  int rem = idx / (C_ * H_);
  int e = rem % E_;
  int n = rem / E_;
  int base = (n * E_ + e) * M_;
  float acc = 0.f;
#pragma unroll
  for (int m = 0; m < M_; ++m) {
    int p = mpos[base + m] + 1;
    acc += att[(((size_t)n * H_ + h) * C_ + p) * C_ + c];
  }
  ent_att[idx] = acc / 3.0f;
}

// ---------------------------------------------------------------- C: ht_att
__global__ void k_ht_att(const float* __restrict__ ent_att, const int* __restrict__ hts,
                         float* __restrict__ ht) {
  int np = blockIdx.x;                 // 0..3199
  int n = np / P_;
  int hi = hts[np * 2 + 0], ti = hts[np * 2 + 1];
  const float* ea_h = ent_att + (size_t)(n * E_ + hi) * H_ * C_;
  const float* ea_t = ent_att + (size_t)(n * E_ + ti) * H_ * C_;
  const int t = threadIdx.x;           // 0..63
  float4 v[4];
  float local = 0.f;
#pragma unroll
  for (int q = 0; q < 4; ++q) {
    int c = t * 4 + 256 * q;
    float4 a = {0.f, 0.f, 0.f, 0.f};
#pragma unroll
    for (int h = 0; h < H_; ++h) {
      float4 x = *(const float4*)(ea_h + (size_t)h * C_ + c);
      float4 y = *(const float4*)(ea_t + (size_t)h * C_ + c);
      a.x += x.x * y.x; a.y += x.y * y.y; a.z += x.z * y.z; a.w += x.w * y.w;
    }
    a.x /= 12.f; a.y /= 12.f; a.z /= 12.f; a.w /= 12.f;
    v[q] = a;
    local += a.x + a.y + a.z + a.w;
  }
  float s = local;
#pragma unroll
  for (int m = 32; m > 0; m >>= 1) s += __shfl_xor(s, m);
  float S = s + 1e-5f;
#pragma unroll
  for (int q = 0; q < 4; ++q) {
    int c = t * 4 + 256 * q;
    float4 o;
    o.x = v[q].x / S; o.y = v[q].y / S; o.z = v[q].z / S; o.w = v[q].w / S;
    *(float4*)&ht[(size_t)np * C_ + c] = o;
  }
}

// ---------------------------------------------------------------- D (fallback): rs GEMM
__global__ void k_rs(const float* __restrict__ ht, const float* __restrict__ seq,
                     float* __restrict__ rs) {
  const int pt0 = blockIdx.x * 16;     // 200 tiles
  const int n = pt0 / P_;
  const int ot = threadIdx.x & 63;
  const int jt = threadIdx.x >> 6;     // 0..3
  const int o4 = blockIdx.y * 256 + ot * 4;
  __shared__ float hlds[16 * 66];
  float4 a32[4];
  double a64[4][4];
#pragma unroll
  for (int q = 0; q < 4; ++q) {
    a32[q] = {0.f, 0.f, 0.f, 0.f};
#pragma unroll
    for (int i = 0; i < 4; ++i) a64[q][i] = 0.0;
  }
  const float* seqn = seq + (size_t)n * C_ * D_;
  for (int c0 = 0; c0 < C_; c0 += 64) {
    for (int l = threadIdx.x; l < 1024; l += 256) {
      int j = l >> 6, cc = l & 63;
      hlds[j * 66 + cc] = ht[(size_t)(pt0 + j) * C_ + c0 + cc];
    }
    __syncthreads();
#pragma unroll 4
    for (int cc = 0; cc < 64; ++cc) {
      float4 sv = *(const float4*)&seqn[(size_t)(c0 + cc) * D_ + o4];
#pragma unroll
      for (int q = 0; q < 4; ++q) {
        float w = hlds[(jt * 4 + q) * 66 + cc];
        a32[q].x += w * sv.x; a32[q].y += w * sv.y;
        a32[q].z += w * sv.z; a32[q].w += w * sv.w;
      }
    }
#pragma unroll
    for (int q = 0; q < 4; ++q) {
      a64[q][0] += (double)a32[q].x; a64[q][1] += (double)a32[q].y;
      a64[q][2] += (double)a32[q].z; a64[q][3] += (double)a32[q].w;
      a32[q] = {0.f, 0.f, 0.f, 0.f};
    }
    __syncthreads();
  }
#pragma unroll
  for (int q = 0; q < 4; ++q) {
    int p = pt0 + jt * 4 + q;
#pragma unroll
    for (int i = 0; i < 4; ++i)
      rs[(size_t)p * D_ + o4 + i] = (float)a64[q][i];
  }
}

// ---------------------------------------------------------------- seq-split prep (rs B operand)
__global__ void k_wsplit_rs(const float* __restrict__ seq,
                            unsigned short* __restrict__ Shi,
                            unsigned short* __restrict__ Slo) {
  int g = blockIdx.x * 256 + threadIdx.x;          // 0..393215
  int l = g & 63;
  int n = (g >> 6) % 48;
  int T = (g >> 6) / 48 % 32;
  int doc = g / 98304;
  int k0 = T * 32 + (l >> 4) * 8;
  int o = n * 16 + (l & 15);
  size_t off = (size_t)g * 8;
#pragma unroll
  for (int e = 0; e < 8; ++e) {
    float v = seq[((size_t)doc * C_ + k0 + e) * D_ + o];
    unsigned short hi = f2bf(v);
    unsigned short lo = f2bf(v - bf2f(hi));
    Shi[off + e] = hi;
    Slo[off + e] = lo;
  }
}

// ---------------------------------------------------------------- D': rs via MFMA
__global__ __launch_bounds__(256) void k_rs_mfma(
    const float* __restrict__ ht,
    const unsigned short* __restrict__ Shi, const unsigned short* __restrict__ Slo,
    float* __restrict__ rs) {
  const int pt  = blockIdx.x;          // 0..99
  const int doc = pt / 25;
  const int n0  = blockIdx.y * 12;
  const int tid = threadIdx.x;
  const int w   = tid >> 6;
  const int l   = tid & 63;
  const int rg  = w & 1, cg = w >> 1;
  const int kg  = l >> 4;
  const int pr  = pt * 32 + rg * 16 + (l & 15);
  const float* htrow = ht + (size_t)pr * C_;

  __shared__ __align__(16) unsigned short ldsW[2][12288];  // 2 x 24576 B

  auto stage = [&](int buf, int T) {
#pragma unroll
    for (int rr = 0; rr < 6; ++rr) {
      int u = rr * 256 + tid;          // 0..1535
      int term = u / 768, rem = u % 768;
      int nn = rem >> 6, lu = rem & 63;
      const unsigned short* src = (term ? Slo : Shi) +
          (((size_t)(doc * 32 + T) * 48 + n0 + nn) * 64 + lu) * 8;
      GLOAD_LDS16(src, &ldsW[buf][u * 8]);
    }
  };

  f32x4 acc[6];
#pragma unroll
  for (int nn = 0; nn < 6; ++nn) acc[nn] = (f32x4){0.f, 0.f, 0.f, 0.f};

  stage(0, 0);
  __syncthreads();

  int cur = 0;
#pragma unroll 1
  for (int T = 0; T < 32; ++T) {
    if (T < 31) stage(cur ^ 1, T + 1);

    int kx = T * 32 + kg * 8;
    float4 z0 = *(const float4*)(htrow + kx);
    float4 z1 = *(const float4*)(htrow + kx + 4);
    float zv[8] = {z0.x, z0.y, z0.z, z0.w, z1.x, z1.y, z1.z, z1.w};
    bf16x8 ahi, alo;
    split8(zv, &ahi, &alo);

    const unsigned short* lp = ldsW[cur];
#pragma unroll
    for (int nn = 0; nn < 6; ++nn) {
      int nt = cg * 6 + nn;
      bf16x8 bh = *(const bf16x8*)(lp + ((size_t)(nt * 64 + l)) * 8);
      bf16x8 bl = *(const bf16x8*)(lp + 6144 + ((size_t)(nt * 64 + l)) * 8);
      acc[nn] = __builtin_amdgcn_mfma_f32_16x16x32_bf16(ahi, bh, acc[nn], 0, 0, 0);
      acc[nn] = __builtin_amdgcn_mfma_f32_16x16x32_bf16(ahi, bl, acc[nn], 0, 0, 0);
      acc[nn] = __builtin_amdgcn_mfma_f32_16x16x32_bf16(alo, bh, acc[nn], 0, 0, 0);
    }
    __syncthreads();
    cur ^= 1;
  }

  const int colr = l & 15, rowg = (l >> 4) * 4;
#pragma unroll
  for (int nn = 0; nn < 6; ++nn)
#pragma unroll
    for (int i = 0; i < 4; ++i) {
      int p = pt * 32 + rg * 16 + rowg + i;
      int o = (n0 + cg * 6 + nn) * 16 + colr;
      rs[(size_t)p * D_ + o] = acc[nn][i];
    }
}

// ---------------------------------------------------------------- E (fallback): zh & zt merged
__global__ void k_zht(const float* __restrict__ ent_emb, const float* __restrict__ rs,
                      const int* __restrict__ hts,
                      const float* __restrict__ Wh_, const float* __restrict__ bh_,
                      const float* __restrict__ Wt_, const float* __restrict__ bt_,
                      float* __restrict__ zh_, float* __restrict__ zt_) {
  const int which = blockIdx.z;        // 0 -> zh, 1 -> zt
  const float* W    = which ? Wt_ : Wh_;
  const float* bias = which ? bt_ : bh_;
  float* out        = which ? zt_ : zh_;
  const int dbl_tanh = which ^ 1;
  const int pt0 = blockIdx.x * 16;
  const int n = pt0 / P_;
  const int ot = threadIdx.x & 63;
  const int jt = threadIdx.x >> 6;
  const int o4 = blockIdx.y * 256 + ot * 4;
  __shared__ float xlds[16 * 66];
  __shared__ int sidx[16];
  if (threadIdx.x < 16) sidx[threadIdx.x] = hts[(pt0 + threadIdx.x) * 2 + which];
  float4 a32[4];
  double a64[4][4];
#pragma unroll
  for (int q = 0; q < 4; ++q) {
    a32[q] = {0.f, 0.f, 0.f, 0.f};
#pragma unroll
    for (int i = 0; i < 4; ++i) a64[q][i] = 0.0;
  }
  __syncthreads();
  for (int k0 = 0; k0 < IN2_; k0 += 64) {
    for (int l = threadIdx.x; l < 1024; l += 256) {
      int j = l >> 6, q = l & 63;
      int kx = k0 + q;
      float val;
      if (kx < D_) val = ent_emb[(size_t)(n * E_ + sidx[j]) * D_ + kx];
      else         val = rs[(size_t)(pt0 + j) * D_ + (kx - D_)];
      xlds[j * 66 + q] = val;
    }
    __syncthreads();
#pragma unroll 4
    for (int q = 0; q < 64; ++q) {
      float4 wv = *(const float4*)&W[(size_t)(k0 + q) * EMB_ + o4];
#pragma unroll
      for (int j = 0; j < 4; ++j) {
        float x = xlds[(jt * 4 + j) * 66 + q];
        a32[j].x += x * wv.x; a32[j].y += x * wv.y;
        a32[j].z += x * wv.z; a32[j].w += x * wv.w;
      }
    }
#pragma unroll
    for (int j = 0; j < 4; ++j) {
      a64[j][0] += (double)a32[j].x; a64[j][1] += (double)a32[j].y;
      a64[j][2] += (double)a32[j].z; a64[j][3] += (double)a32[j].w;
      a32[j] = {0.f, 0.f, 0.f, 0.f};
    }
    __syncthreads();
  }
#pragma unroll
  for (int j = 0; j < 4; ++j) {
    int p = pt0 + jt * 4 + j;
#pragma unroll
    for (int i = 0; i < 4; ++i) {
      int o = o4 + i;
      double z = a64[j][i] + (double)bias[o];
      z = tanh(z);
      if (dbl_tanh) z = tanh(z);
      out[(size_t)p * EMB_ + o] = (float)z;
    }
  }
}

// ---------------------------------------------------------------- W-split prep (logits Wb)
__global__ void k_wsplit(const float* __restrict__ Wb,
                         unsigned short* __restrict__ Whi,
                         unsigned short* __restrict__ Wlo) {
  int g = blockIdx.x * 256 + threadIdx.x;          // 0..589823
  int l = g & 63;
  int n = (g >> 6) % 6;
  int T = (g >> 6) / 6 % 128;
  int k12 = g / 49152;
  int kk = (T >> 1) * 64 + (T & 1) * 32 + (l >> 4) * 8;
  int row0 = k12 * 4096 + kk;
  int r = n * 16 + (l & 15);
  size_t o = (size_t)g * 8;
#pragma unroll
  for (int e = 0; e < 8; ++e) {
    float v = Wb[(size_t)(row0 + e) * NREL_ + r];
    unsigned short hi = f2bf(v);
    unsigned short lo = f2bf(v - bf2f(hi));
    Whi[o + e] = hi;
    Wlo[o + e] = lo;
  }
}

// ---------------------------------------------------------------- pack W col 96
__global__ void k_pack96(const float* __restrict__ Wb, float* __restrict__ W96c) {
  int g = blockIdx.x * 256 + threadIdx.x;          // 0..49151
  W96c[g] = Wb[(size_t)g * NREL_ + 96];
}

// ---------------------------------------------------------------- W-split prep (zht Wh/Wt)
__global__ void k_wsplit_zht(const float* __restrict__ Wh_, const float* __restrict__ Wt_,
                             unsigned short* __restrict__ Zhi,
                             unsigned short* __restrict__ Zlo) {
  int g = blockIdx.x * 256 + threadIdx.x;          // 0..294911
  int which = g / 147456;
  int rem = g % 147456;
  int l = rem & 63;
  int n = (rem >> 6) % 48;
  int T = (rem >> 6) / 48;
  const float* W = which ? Wt_ : Wh_;
  int k0 = T * 32 + (l >> 4) * 8;
  int o = n * 16 + (l & 15);
  size_t off = ((size_t)which * 147456 + (size_t)(T * 48 + n) * 64 + l) * 8;
#pragma unroll
  for (int e = 0; e < 8; ++e) {
    float v = W[(size_t)(k0 + e) * EMB_ + o];
    unsigned short hi = f2bf(v);
    unsigned short lo = f2bf(v - bf2f(hi));
    Zhi[off + e] = hi;
    Zlo[off + e] = lo;
  }
}

// ---------------------------------------------------------------- E': zh & zt via MFMA
// A-operand (eb/rb slice) register-prefetched one chunk ahead: its global-load
// latency hides under the MFMA cluster + barrier drain instead of being
// exposed serially at the top of each chunk. Value-identical math.
__global__ __launch_bounds__(256) void k_zht_mfma(
    const float* __restrict__ ent_emb, const float* __restrict__ rs,
    const int* __restrict__ hts,
    const unsigned short* __restrict__ Zhi, const unsigned short* __restrict__ Zlo,
    const float* __restrict__ bh_, const float* __restrict__ bt_,
    float* __restrict__ zh_, float* __restrict__ zt_) {
  const int which = blockIdx.z;
  const float* bias = which ? bt_ : bh_;
  float* out = which ? zt_ : zh_;
  const int ptb = blockIdx.x * 64;
  const int n0  = blockIdx.y * 6;      // ntile base (o base = n0*16)
  const int tid = threadIdx.x;
  const int w   = tid >> 6;
  const int l   = tid & 63;
  const int kg  = l >> 4;
  const int pr  = ptb + w * 16 + (l & 15);
  const int doc = pr / P_;
  const int idx = hts[pr * 2 + which];
  const float* eb = ent_emb + (size_t)(doc * E_ + idx) * D_;
  const float* rb = rs + (size_t)pr * D_;

  __shared__ __align__(16) unsigned short ldsW[2][6144];  // 2 x 12288 B

  const unsigned short* Zh = Zhi + (size_t)which * 147456 * 8;
  const unsigned short* Zl = Zlo + (size_t)which * 147456 * 8;

  auto stage = [&](int buf, int T) {
#pragma unroll
    for (int rr = 0; rr < 3; ++rr) {
      int u = rr * 256 + tid;
      int term = u / 384, rem = u % 384;
      int nn = rem >> 6, lu = rem & 63;
      const unsigned short* src = (term ? Zl : Zh) +
          ((size_t)(T * 48 + n0 + nn) * 64 + lu) * 8;
      GLOAD_LDS16(src, &ldsW[buf][u * 8]);
    }
  };
  auto aload = [&](int T, float4* z0, float4* z1) {
    int kx = T * 32 + kg * 8;
    const float* src = (T < 24) ? (eb + kx) : (rb + kx - D_);
    *z0 = *(const float4*)(src);
    *z1 = *(const float4*)(src + 4);
  };

  f32x4 acc[6];
#pragma unroll
  for (int nn = 0; nn < 6; ++nn) acc[nn] = (f32x4){0.f, 0.f, 0.f, 0.f};

  stage(0, 0);
  float4 z0, z1;
  aload(0, &z0, &z1);
  __syncthreads();

  int cur = 0;
#pragma unroll 1
  for (int T = 0; T < 48; ++T) {
    if (T < 47) stage(cur ^ 1, T + 1);

    float zv[8] = {z0.x, z0.y, z0.z, z0.w, z1.x, z1.y, z1.z, z1.w};
    bf16x8 ahi, alo;
    split8(zv, &ahi, &alo);
    if (T < 47) aload(T + 1, &z0, &z1);    // prefetch next A (overlaps MFMAs)

    const unsigned short* lp = ldsW[cur];
#pragma unroll
    for (int nn = 0; nn < 6; ++nn) {
      bf16x8 bh = *(const bf16x8*)(lp + ((size_t)(nn * 64 + l)) * 8);
      bf16x8 bl = *(const bf16x8*)(lp + ((size_t)(384 + nn * 64 + l)) * 8);
      acc[nn] = __builtin_amdgcn_mfma_f32_16x16x32_bf16(ahi, bh, acc[nn], 0, 0, 0);
      acc[nn] = __builtin_amdgcn_mfma_f32_16x16x32_bf16(ahi, bl, acc[nn], 0, 0, 0);
      acc[nn] = __builtin_amdgcn_mfma_f32_16x16x32_bf16(alo, bh, acc[nn], 0, 0, 0);
    }
    __syncthreads();
    cur ^= 1;
  }

  const int colr = l & 15, rowg = (l >> 4) * 4;
#pragma unroll
  for (int nn = 0; nn < 6; ++nn)
#pragma unroll
    for (int i = 0; i < 4; ++i) {
      int p = ptb + w * 16 + rowg + i;
      int o = (n0 + nn) * 16 + colr;
      double z = (double)acc[nn][i] + (double)bias[o];
      z = tanh(z);
      if (which == 0) z = tanh(z);
      out[(size_t)p * EMB_ + o] = (float)z;
    }
}

// ---------------------------------------------------------------- F: logits via MFMA (r 0..95)
// R21 shape (256 thr, 4 waves, 64-pair tiles, 1200 blocks) + A-operand
// register prefetch one chunk ahead. Sum order and partials bit-identical.
__global__ __launch_bounds__(256) void k_logits_mfma(
    const float* __restrict__ zh, const float* __restrict__ zt,
    const unsigned short* __restrict__ Whi, const unsigned short* __restrict__ Wlo,
    float* __restrict__ pA) {
  const int bid = blockIdx.x;          // 0..1199
  const int s   = bid % 24;            // slab (XCD s%8 affinity)
  const int ptb = (bid / 24) * 64;     // pair-tile base
  const int k12 = s >> 1, q = s & 1;
  const int tid = threadIdx.x;
  const int w   = tid >> 6;
  const int l   = tid & 63;
  const int kg  = l >> 4;
  const int pr  = ptb + w * 16 + (l & 15);

  __shared__ __align__(16) unsigned short ldsW[2][6144];

  auto stage = [&](int buf, int tl) {
    int T = q * 64 + tl;
    size_t fb = (size_t)(k12 * 128 + T) * 6;
#pragma unroll
    for (int rr = 0; rr < 3; ++rr) {
      int u = rr * 256 + tid;
      int term = u / 384, rem = u % 384;
      int n = rem >> 6, lu = rem & 63;
      const unsigned short* src = (term ? Wlo : Whi) + ((fb + n) * 64 + lu) * 8;
      GLOAD_LDS16(src, &ldsW[buf][u * 8]);
    }
  };

  f32x4 acc[6];
#pragma unroll
  for (int n = 0; n < 6; ++n) acc[n] = (f32x4){0.f, 0.f, 0.f, 0.f};

  const float* ztrow = zt + (size_t)pr * EMB_ + k12 * 64;
  const float* zhrow = zh + (size_t)pr * EMB_ + k12 * 64;

  auto aload = [&](int tl, float4* z0, float4* z1, float* zhv) {
    int T = q * 64 + tl;
    *zhv = zhrow[T >> 1];
    int cbase = (T & 1) * 32 + kg * 8;
    *z0 = *(const float4*)(ztrow + cbase);
    *z1 = *(const float4*)(ztrow + cbase + 4);
  };

  stage(0, 0);
  float4 z0, z1;
  float zhv;
  aload(0, &z0, &z1, &zhv);
  __syncthreads();

  int cur = 0;
#pragma unroll 1
  for (int tl = 0; tl < 64; ++tl) {
    if (tl < 63) stage(cur ^ 1, tl + 1);

    float pz[8] = {zhv * z0.x, zhv * z0.y, zhv * z0.z, zhv * z0.w,
                   zhv * z1.x, zhv * z1.y, zhv * z1.z, zhv * z1.w};
    bf16x8 ahi, alo;
    split8(pz, &ahi, &alo);
    if (tl < 63) aload(tl + 1, &z0, &z1, &zhv);   // prefetch next A

    const unsigned short* lp = ldsW[cur];
#pragma unroll
    for (int n = 0; n < 6; ++n) {
      bf16x8 bh = *(const bf16x8*)(lp + ((size_t)(n * 64 + l)) * 8);
      bf16x8 bl = *(const bf16x8*)(lp + ((size_t)(384 + n * 64 + l)) * 8);
      acc[n] = __builtin_amdgcn_mfma_f32_16x16x32_bf16(ahi, bh, acc[n], 0, 0, 0);
      acc[n] = __builtin_amdgcn_mfma_f32_16x16x32_bf16(ahi, bl, acc[n], 0, 0, 0);
      acc[n] = __builtin_amdgcn_mfma_f32_16x16x32_bf16(alo, bh, acc[n], 0, 0, 0);
    }
    __syncthreads();
    cur ^= 1;
  }

  float* po = pA + (size_t)s * NP_ * NREL_;
  const int colr = l & 15, rowg = (l >> 4) * 4;
#pragma unroll
  for (int n = 0; n < 6; ++n)
#pragma unroll
    for (int i = 0; i < 4; ++i) {
      int p = ptb + w * 16 + rowg + i;
      po[(size_t)p * NREL_ + n * 16 + colr] = acc[n][i];
    }
}

// ---------------------------------------------------------------- F2: r=96 (packed W96c, block per pair)
__global__ void k_r96b(const float* __restrict__ zh, const float* __restrict__ zt,
                       const float* __restrict__ W96c, float* __restrict__ r96o) {
  const int p = blockIdx.x;            // 0..3199
  const int t = threadIdx.x;           // 0..255
  const float* zhr = zh + (size_t)p * EMB_;
  const float* ztr = zt + (size_t)p * EMB_;
  float acc = 0.f;
#pragma unroll
  for (int i = 0; i < 3; ++i) {
    int kk = t + 256 * i;
    float zhv = zhr[kk];
    const float* wseg = W96c + kk * 64;
    const float* zseg = ztr + (kk >> 6) * 64;
    float d = 0.f;
#pragma unroll
    for (int c4 = 0; c4 < 16; ++c4) {
      float4 wv = *(const float4*)(wseg + c4 * 4);
      float4 zv = *(const float4*)(zseg + c4 * 4);
      d += wv.x * zv.x + wv.y * zv.y + wv.z * zv.z + wv.w * zv.w;
    }
    acc += zhv * d;
  }
  __shared__ double red[256];
  red[t] = (double)acc;
  __syncthreads();
  for (int s = 128; s > 0; s >>= 1) {
    if (t < s) red[t] += red[t + s];
    __syncthreads();
  }
  if (t == 0) r96o[p] = (float)red[0];
}

// ---------------------------------------------------------------- G: finalize (MFMA path)
__global__ void k_final_mfma(const float* __restrict__ pA, const float* __restrict__ r96o,
                             const float* __restrict__ bb, float* __restrict__ out) {
  const int p = blockIdx.x;
  const int r = threadIdx.x;           // 128 threads
  __shared__ double th_s;
  __shared__ int cnt[128];
  double v = 0.0;
  if (r < 96) {
    for (int g = 0; g < 24; ++g)
      v += (double)pA[(size_t)g * NP_ * NREL_ + (size_t)p * NREL_ + r];
    v += (double)bb[r];
    out[(size_t)p * NREL_ + r] = (float)v;
  } else if (r == 96) {
    v = (double)r96o[p] + (double)bb[96];
    out[(size_t)p * NREL_ + 96] = (float)v;
  }
  if (r == 0) th_s = v;
  __syncthreads();
  int pred = (r >= 1 && r < NREL_ && v > th_s) ? 1 : 0;
  cnt[r] = pred;
  __syncthreads();
  for (int s = 64; s > 0; s >>= 1) {
    if (r < s) cnt[r] += cnt[r + s];
    __syncthreads();
  }
  if (r < NREL_) {
    float pv = (r == 0) ? ((cnt[0] == 0) ? 1.f : 0.f) : (float)pred;
    out[(size_t)NP_ * NREL_ + (size_t)p * NREL_ + r] = pv;
  }
}

// ---------------------------------------------------------------- Fallback flat logits + final
__global__ __launch_bounds__(256) void k_logits_flat(
    const float* __restrict__ zh, const float* __restrict__ zt,
    const float* __restrict__ Wb, float* __restrict__ part) {
  const int bid = blockIdx.x;
  const int s   = bid % 24;
  const int t   = bid / 24;
  const int k   = s >> 1, bh = s & 1;
  const int pt0 = t * 64;
  const int rt = threadIdx.x & 15;
  const int pg = threadIdx.x >> 4;
  const int kb0 = k * 64 + bh * 32;
  __shared__ float Wlin[64 * 97];
  auto stage_w = [&](int b) {
    const float* src = Wb + (size_t)(kb0 + b) * 6208;
#pragma unroll
    for (int u = 0; u < 6; ++u)
      GLOAD_LDS16(src + (u * 256 + threadIdx.x) * 4,
                  Wlin + (u * 256 + threadIdx.x) * 4);
    if (threadIdx.x < 16)
      GLOAD_LDS16(src + (1536 + threadIdx.x) * 4,
                  Wlin + (1536 + threadIdx.x) * 4);
  };
  stage_w(0);
  float acc[4][6];
  float acc6[4];
#pragma unroll
  for (int j = 0; j < 4; ++j) {
    acc6[j] = 0.f;
#pragma unroll
    for (int i = 0; i < 6; ++i) acc[j][i] = 0.f;
  }
  const float* ztb  = zt + (size_t)(pt0 + pg * 4) * EMB_ + k * 64;
  const float* zh_g = zh + (size_t)(pt0 + pg * 4) * EMB_ + kb0;
  __syncthreads();
#pragma unroll 1
  for (int b = 0; b < 32; ++b) {
    float zhv[4];
#pragma unroll
    for (int j = 0; j < 4; ++j) zhv[j] = zh_g[(size_t)j * EMB_ + b];
#pragma unroll 1
    for (int c0 = 0; c0 < 64; c0 += 4) {
      float4 ztv[4];
#pragma unroll
      for (int j = 0; j < 4; ++j)
        ztv[j] = *(const float4*)(ztb + (size_t)j * EMB_ + c0);
      float4 pz[4];
#pragma unroll
      for (int j = 0; j < 4; ++j) {
        pz[j].x = zhv[j] * ztv[j].x; pz[j].y = zhv[j] * ztv[j].y;
        pz[j].z = zhv[j] * ztv[j].z; pz[j].w = zhv[j] * ztv[j].w;
      }
#pragma unroll
      for (int cc = 0; cc < 4; ++cc) {
        const float* wr = &Wlin[(c0 + cc) * 97];
        float w6 = wr[96];
#pragma unroll
        for (int i = 0; i < 6; ++i) {
          float w = wr[rt + 16 * i];
#pragma unroll
          for (int j = 0; j < 4; ++j) {
            float pzc = (cc == 0) ? pz[j].x : (cc == 1) ? pz[j].y
                      : (cc == 2) ? pz[j].z : pz[j].w;
            acc[j][i] += pzc * w;
          }
        }
#pragma unroll
        for (int j = 0; j < 4; ++j) {
          float pzc = (cc == 0) ? pz[j].x : (cc == 1) ? pz[j].y
                    : (cc == 2) ? pz[j].z : pz[j].w;
          acc6[j] += pzc * w6;
        }
      }
    }
    if (b < 31) {
      __syncthreads();
      stage_w(b + 1);
      __syncthreads();
    }
  }
  float* po = part + (size_t)s * NP_ * NREL_;
#pragma unroll
  for (int j = 0; j < 4; ++j) {
    int p = pt0 + pg * 4 + j;
#pragma unroll
    for (int i = 0; i < 6; ++i)
      po[(size_t)p * NREL_ + rt + 16 * i] = acc[j][i];
    if (rt == 0) po[(size_t)p * NREL_ + 96] = acc6[j];
  }
}

__global__ void k_final_flat(const float* __restrict__ part, const float* __restrict__ bb,
                             float* __restrict__ out) {
  const int p = blockIdx.x;
  const int r = threadIdx.x;
  __shared__ double th_s;
  __shared__ int cnt[128];
  double v = 0.0;
  if (r < NREL_) {
    for (int g = 0; g < 24; ++g)
      v += (double)part[(size_t)g * NP_ * NREL_ + (size_t)p * NREL_ + r];
    v += (double)bb[r];
    out[(size_t)p * NREL_ + r] = (float)v;
  }
  if (r == 0) th_s = v;
  __syncthreads();
  int pred = (r >= 1 && r < NREL_ && v > th_s) ? 1 : 0;
  cnt[r] = pred;
  __syncthreads();
  for (int s = 64; s > 0; s >>= 1) {
    if (r < s) cnt[r] += cnt[r + s];
    __syncthreads();
  }
  if (r < NREL_) {
    float pv = (r == 0) ? ((cnt[0] == 0) ? 1.f : 0.f) : (float)pred;
    out[(size_t)NP_ * NREL_ + (size_t)p * NREL_ + r] = pv;
  }
}

extern "C" void kernel_launch(void* const* d_in, const int* in_sizes, int n_in,
                              void* d_out, int out_size, void* d_ws, size_t ws_size,
                              hipStream_t stream) {
  const float* seq  = (const float*)d_in[0];
  const float* att  = (const float*)d_in[1];
  const int*   mpos = (const int*)d_in[2];
  const int*   hts  = (const int*)d_in[3];
  const float* Wh   = (const float*)d_in[4];
  const float* bh   = (const float*)d_in[5];
  const float* Wt   = (const float*)d_in[6];
  const float* bt   = (const float*)d_in[7];
  const float* Wb   = (const float*)d_in[8];
  const float* bb   = (const float*)d_in[9];
  float* out = (float*)d_out;
  float* ws = (float*)d_ws;

  float* ent_emb = ws;                   // [0, 122880)
  float* ent_att = ws + 122880;          // dead after k_ht_att
  float* ht      = ws + 2088960;         // dead after rs
  float* rs      = ws + 5365760;         // dead after zht
  float* zh      = ws + 7823360;
  float* zt      = ws + 10280960;        // ends 12738560
  // MFMA path layout (float-offsets):
  //   pA    [122880, 7572480)      24 slabs (aliases dead ent_att+ht+rs at logits time)
  //   Shi   [7823360, 9396224)     3,145,728 bf16  } alias zh/zt region: dead
  //   Slo   [9396224, 10969088)    3,145,728 bf16  } before k_zht_mfma writes
  //   r96o  [12738560, 12741760)   3200
  //   Whi   [12815360, 15174656)   4,718,592 bf16
  //   Wlo   [15174656, 17533952)   4,718,592 bf16
  //   Zhi   [17533952, 18713600)   2 x 1,179,648 bf16
  //   Zlo   [18713600, 19893248)   2 x 1,179,648 bf16
  //   W96c  [19893248, 19942400)   49152 fp32
  float* pA   = ws + 122880;
  unsigned short* Shi = (unsigned short*)(ws + 7823360);
  unsigned short* Slo = (unsigned short*)(ws + 9396224);
  float* r96o = ws + 12738560;
  unsigned short* Whi = (unsigned short*)(ws + 12815360);
  unsigned short* Wlo = (unsigned short*)(ws + 15174656);
  unsigned short* Zhi = (unsigned short*)(ws + 17533952);
  unsigned short* Zlo = (unsigned short*)(ws + 18713600);
  float* W96c = ws + 19893248;
  const bool big = ws_size >= (size_t)19942400 * sizeof(float);  // 79.8 MB

  if (big) {
    k_wsplit<<<2304, 256, 0, stream>>>(Wb, Whi, Wlo);
    k_wsplit_zht<<<1152, 256, 0, stream>>>(Wh, Wt, Zhi, Zlo);
    k_wsplit_rs<<<1536, 256, 0, stream>>>(seq, Shi, Slo);
    k_pack96<<<192, 256, 0, stream>>>(Wb, W96c);
  }
  k_ent_emb<<<160, 256, 0, stream>>>(seq, mpos, ent_emb);
  k_ent_att<<<7680, 256, 0, stream>>>(att, mpos, ent_att);
  k_ht_att<<<3200, 64, 0, stream>>>(ent_att, hts, ht);
  if (big) {
    k_rs_mfma<<<dim3(100, 4), 256, 0, stream>>>(ht, Shi, Slo, rs);
    k_zht_mfma<<<dim3(50, 8, 2), 256, 0, stream>>>(ent_emb, rs, hts, Zhi, Zlo,
                                                   bh, bt, zh, zt);
    k_r96b<<<3200, 256, 0, stream>>>(zh, zt, W96c, r96o);
    k_logits_mfma<<<1200, 256, 0, stream>>>(zh, zt, Whi, Wlo, pA);
    k_final_mfma<<<3200, 128, 0, stream>>>(pA, r96o, bb, out);
  } else {
    k_rs<<<dim3(200, 3), 256, 0, stream>>>(ht, seq, rs);
    k_zht<<<dim3(200, 3, 2), 256, 0, stream>>>(ent_emb, rs, hts, Wh, bh, Wt, bt, zh, zt);
    k_logits_flat<<<1200, 256, 0, stream>>>(zh, zt, Wb, pA);
    k_final_flat<<<3200, 128, 0, stream>>>(pA, bb, out);
  }
}